// Round 2
// baseline (9281.443 us; speedup 1.0000x reference)
//
#include <hip/hip_runtime.h>
#include <hip/hip_bf16.h>
#include <stdint.h>

#define BB 256
#define TT 128
#define DD 32
#define HH 512
#define NL 6
#define TC 4

typedef __attribute__((ext_vector_type(8))) short short8;
typedef __attribute__((ext_vector_type(4))) float f32x4;

__device__ __forceinline__ unsigned short f2bf(float f) {
    union { float f; unsigned u; } v; v.f = f;
    unsigned r = v.u + 0x7fff + ((v.u >> 16) & 1);
    return (unsigned short)(r >> 16);
}
__device__ __forceinline__ float fsig(float x) { return 1.0f / (1.0f + __expf(-x)); }
__device__ __forceinline__ float ftanh(float x) {
    float e = __expf(-2.0f * fabsf(x));
    float t = (1.0f - e) / (1.0f + e);
    return x < 0.0f ? -t : t;
}

// ---------------- zero the sync counters (no hipMemsetAsync under capture) ----------------
__global__ __launch_bounds__(256) void k_zero(unsigned int* __restrict__ p, int n) {
    int i = blockIdx.x * 256 + threadIdx.x;
    if (i < n) p[i] = 0;
}

// ---------------- weight f32 -> bf16 ----------------
__global__ __launch_bounds__(256) void k_convert(const float* __restrict__ wih, const float* __restrict__ whh,
                                                 unsigned short* __restrict__ wih_bf, unsigned short* __restrict__ whh_bf,
                                                 int n4) {
    int i = blockIdx.x * 256 + threadIdx.x;
    if (i >= n4) return;
    float4 a = ((const float4*)wih)[i];
    float4 b = ((const float4*)whh)[i];
    ushort4 ra; ra.x = f2bf(a.x); ra.y = f2bf(a.y); ra.z = f2bf(a.z); ra.w = f2bf(a.w);
    ushort4 rb; rb.x = f2bf(b.x); rb.y = f2bf(b.y); rb.z = f2bf(b.z); rb.w = f2bf(b.w);
    ((ushort4*)wih_bf)[i] = ra;
    ((ushort4*)whh_bf)[i] = rb;
}

// ---------------- input projection: hprev = x @ w_proj.T + b ----------------
__global__ __launch_bounds__(512) void k_proj(const float* __restrict__ x, const float* __restrict__ wp,
                                              const float* __restrict__ bp,
                                              float* __restrict__ hprev, unsigned short* __restrict__ abf) {
    __shared__ float xs[64][DD];
    int m0 = blockIdx.x * 64;
    for (int i = threadIdx.x; i < 64 * DD; i += 512)
        xs[i >> 5][i & 31] = x[(size_t)(m0 + (i >> 5)) * DD + (i & 31)];
    __syncthreads();
    int n = threadIdx.x;
    float w[DD];
#pragma unroll
    for (int k = 0; k < DD; k++) w[k] = wp[n * DD + k];
    float bias = bp[n];
    for (int r = 0; r < 64; r++) {
        float acc = bias;
#pragma unroll
        for (int k = 0; k < DD; k++) acc += xs[r][k] * w[k];
        size_t o = (size_t)(m0 + r) * HH + n;
        hprev[o] = acc;
        abf[o] = f2bf(acc);
    }
}

// ---------------- fused persistent LSTM layer ----------------
// 128 blocks; block -> (bx: batch group of 64, ux: 16-unit tile).
// whh slice (64 rows x 512) resident in LDS (XOR swizzle). x-part GEMM fused,
// computed in chunks of TC timesteps with w_ih B-fragments streamed from L2.
// Sync: per-bx counter (32 blocks each), release/acquire, h via bf16 ping-pong.
__global__ __launch_bounds__(256) void k_lstm_fused(const unsigned short* __restrict__ wih_bf,  // [2048][512]
                                                    const unsigned short* __restrict__ whh_bf,  // [2048][512]
                                                    const unsigned short* __restrict__ a_bf,    // [B*T][512]
                                                    const float* __restrict__ bih, const float* __restrict__ bhh,
                                                    unsigned short* __restrict__ hbuf,          // [2][256][512]
                                                    float* __restrict__ lstm_o,                 // [B*T][512]
                                                    unsigned int* __restrict__ cnt) {           // 4 counters, 64 u32 apart
    __shared__ unsigned short smem[64 * 512];  // 64 KB whh slice, swizzled
    const int blk = blockIdx.x;
    const int bx = (blk & 7) >> 1;              // same-bx blocks share blk%8 in {2bx,2bx+1}
    const int ux = ((blk >> 3) << 1) | (blk & 1);
    const int tid = threadIdx.x, lane = tid & 63, w = tid >> 6;
    const int u0 = ux * 16;
    const int b0 = bx * 64 + w * 16;
    const int uu = lane & 15;
    const int kg = lane >> 4;
    unsigned int* cntp = cnt + bx * 64;

    // stage whh slice: LDS row rr (gate=rr>>4, unit=u0+(rr&15)), XOR-swizzled
    for (int c = tid; c < 64 * 64; c += 256) {
        int rr = c >> 6, k16 = c & 63;
        int grow = ((rr >> 4) << 9) + u0 + (rr & 15);
        int4 v = *(const int4*)(whh_bf + (size_t)grow * 512 + k16 * 8);
        int baddr = (rr * 1024 + k16 * 16) ^ ((rr & 7) << 4);
        *(int4*)((char*)smem + baddr) = v;
    }
    __syncthreads();

    float biasg[4];
#pragma unroll
    for (int g = 0; g < 4; g++) biasg[g] = bih[(g << 9) + u0 + uu] + bhh[(g << 9) + u0 + uu];

    const int arow = b0 + uu;          // this lane's A-row (batch) for x- and h-fragments
    f32x4 cst = (f32x4){0.f, 0.f, 0.f, 0.f};
    f32x4 xacc[TC][4];

#pragma unroll 1
    for (int tc = 0; tc < TT; tc += TC) {
        // ---- x-part burst: xacc[tt][g] = bias + a[:, tc+tt] @ wih.T ----
#pragma unroll
        for (int tt = 0; tt < TC; tt++)
#pragma unroll
            for (int g = 0; g < 4; g++)
                xacc[tt][g] = (f32x4){biasg[g], biasg[g], biasg[g], biasg[g]};
#pragma unroll
        for (int ks = 0; ks < 16; ks++) {
            short8 bfr[4];
#pragma unroll
            for (int g = 0; g < 4; g++)
                bfr[g] = *(const short8*)(wih_bf + (size_t)((g << 9) + u0 + uu) * 512 + ks * 32 + kg * 8);
#pragma unroll
            for (int tt = 0; tt < TC; tt++) {
                short8 afx = *(const short8*)(a_bf + ((size_t)arow * TT + (tc + tt)) * 512 + ks * 32 + kg * 8);
#pragma unroll
                for (int g = 0; g < 4; g++)
                    xacc[tt][g] = __builtin_amdgcn_mfma_f32_16x16x32_bf16(afx, bfr[g], xacc[tt][g], 0, 0, 0);
            }
        }
        // ---- sequential steps ----
#pragma unroll
        for (int tt = 0; tt < TC; tt++) {
            const int t = tc + tt;
            if (t > 0) {
                if (tid == 0) {
                    unsigned target = 32u * (unsigned)t;
                    int guard = 0;
                    while (__hip_atomic_load(cntp, __ATOMIC_RELAXED, __HIP_MEMORY_SCOPE_AGENT) < target &&
                           ++guard < (1 << 18)) {}
                    (void)__hip_atomic_load(cntp, __ATOMIC_ACQUIRE, __HIP_MEMORY_SCOPE_AGENT);
                }
                __syncthreads();
                const unsigned short* hp = hbuf + (size_t)((t - 1) & 1) * (256 * 512);
                short8 ah[16];
#pragma unroll
                for (int ks = 0; ks < 16; ks++)
                    ah[ks] = *(const short8*)(hp + (size_t)arow * 512 + ks * 32 + kg * 8);
#pragma unroll
                for (int ks = 0; ks < 16; ks++) {
                    const int k2 = (ks * 32 + kg * 8) * 2;
#pragma unroll
                    for (int g = 0; g < 4; g++) {
                        const int rr = (g << 4) + uu;
                        const int baddr = (rr * 1024 + k2) ^ ((rr & 7) << 4);
                        short8 bh = *(const short8*)((const char*)smem + baddr);
                        xacc[tt][g] = __builtin_amdgcn_mfma_f32_16x16x32_bf16(ah[ks], bh, xacc[tt][g], 0, 0, 0);
                    }
                }
            }
            // activations: lane owns unit u0+uu, batches b0+kg*4+r
            unsigned short* hw = hbuf + (size_t)(t & 1) * (256 * 512);
#pragma unroll
            for (int r = 0; r < 4; r++) {
                float i_ = fsig(xacc[tt][0][r]);
                float f_ = fsig(xacc[tt][1][r]);
                float g_ = ftanh(xacc[tt][2][r]);
                float o_ = fsig(xacc[tt][3][r]);
                float c = f_ * cst[r] + i_ * g_;
                cst[r] = c;
                float h = o_ * ftanh(c);
                int b = b0 + kg * 4 + r;
                lstm_o[((size_t)b * TT + t) * 512 + u0 + uu] = h;
                hw[(size_t)b * 512 + u0 + uu] = f2bf(h);
            }
            if (t < TT - 1) {
                __syncthreads();
                if (tid == 0)
                    __hip_atomic_fetch_add(cntp, 1u, __ATOMIC_RELEASE, __HIP_MEMORY_SCOPE_AGENT);
            }
        }
    }
}

// ---------------- LayerNorm + residual; also emit bf16 copy for next layer ----------------
__global__ __launch_bounds__(256) void k_ln(const float* __restrict__ xin, const float* __restrict__ resid,
                                            const float* __restrict__ g, const float* __restrict__ bta,
                                            float* __restrict__ hnew, unsigned short* __restrict__ abf,
                                            int do_res) {
    int row = blockIdx.x * 4 + (threadIdx.x >> 6);
    int lane = threadIdx.x & 63;
    const float* xr = xin + (size_t)row * 512;
    float vals[8];
    float s = 0.f, ss = 0.f;
#pragma unroll
    for (int i = 0; i < 2; i++) {
        float4 t = *(const float4*)(xr + lane * 8 + i * 4);
        vals[i * 4 + 0] = t.x; vals[i * 4 + 1] = t.y; vals[i * 4 + 2] = t.z; vals[i * 4 + 3] = t.w;
        s += t.x + t.y + t.z + t.w;
        ss += t.x * t.x + t.y * t.y + t.z * t.z + t.w * t.w;
    }
#pragma unroll
    for (int off = 32; off > 0; off >>= 1) {
        s += __shfl_down(s, off);
        ss += __shfl_down(ss, off);
    }
    s = __shfl(s, 0); ss = __shfl(ss, 0);
    float mu = s * (1.f / 512.f);
    float var = ss * (1.f / 512.f) - mu * mu;
    float rs = rsqrtf(var + 1e-5f);
#pragma unroll
    for (int i = 0; i < 8; i++) {
        int u = lane * 8 + i;
        float y = (vals[i] - mu) * rs * g[u] + bta[u];
        if (do_res) y += resid[(size_t)row * 512 + u];
        hnew[(size_t)row * 512 + u] = y;
        abf[(size_t)row * 512 + u] = f2bf(y);
    }
}

// ---------------- MLP head ----------------
__global__ __launch_bounds__(512) void k_mlp1(const float* __restrict__ hprev, const float* __restrict__ w1,
                                              const float* __restrict__ b1, float* __restrict__ z1) {
    __shared__ float xs[512];
    int b = blockIdx.x;
    const float* xr = hprev + ((size_t)b * TT + (TT - 1)) * 512;
    xs[threadIdx.x] = xr[threadIdx.x];
    __syncthreads();
    int n = threadIdx.x;
    const float4* wr = (const float4*)(w1 + (size_t)n * 512);
    float acc = b1[n];
#pragma unroll 4
    for (int k4 = 0; k4 < 128; k4++) {
        float4 wv = wr[k4];
        acc += xs[k4 * 4 + 0] * wv.x + xs[k4 * 4 + 1] * wv.y + xs[k4 * 4 + 2] * wv.z + xs[k4 * 4 + 3] * wv.w;
    }
    z1[(size_t)b * 512 + n] = fmaxf(acc, 0.f);
}

__global__ __launch_bounds__(256) void k_mlp2(const float* __restrict__ z1, const float* __restrict__ w2,
                                              const float* __restrict__ b2, float* __restrict__ z2) {
    __shared__ float xs[512];
    int b = blockIdx.x;
    xs[threadIdx.x] = z1[(size_t)b * 512 + threadIdx.x];
    xs[threadIdx.x + 256] = z1[(size_t)b * 512 + threadIdx.x + 256];
    __syncthreads();
    int n = threadIdx.x;
    const float4* wr = (const float4*)(w2 + (size_t)n * 512);
    float acc = b2[n];
#pragma unroll 4
    for (int k4 = 0; k4 < 128; k4++) {
        float4 wv = wr[k4];
        acc += xs[k4 * 4 + 0] * wv.x + xs[k4 * 4 + 1] * wv.y + xs[k4 * 4 + 2] * wv.z + xs[k4 * 4 + 3] * wv.w;
    }
    z2[(size_t)b * 256 + n] = fmaxf(acc, 0.f);
}

__global__ __launch_bounds__(256) void k_mlp3(const float* __restrict__ z2, const float* __restrict__ w3,
                                              const float* __restrict__ b3, float* __restrict__ outp) {
    __shared__ float red[4];
    int b = blockIdx.x;
    int tid = threadIdx.x;
    float p = z2[(size_t)b * 256 + tid] * w3[tid];
#pragma unroll
    for (int off = 32; off > 0; off >>= 1) p += __shfl_down(p, off);
    if ((tid & 63) == 0) red[tid >> 6] = p;
    __syncthreads();
    if (tid == 0) outp[b] = red[0] + red[1] + red[2] + red[3] + b3[0];
}

extern "C" void kernel_launch(void* const* d_in, const int* in_sizes, int n_in,
                              void* d_out, int out_size, void* d_ws, size_t ws_size,
                              hipStream_t stream) {
    const float* x      = (const float*)d_in[0];
    const float* w_proj = (const float*)d_in[1];
    const float* b_proj = (const float*)d_in[2];
    const float* w_ih   = (const float*)d_in[3];
    const float* w_hh   = (const float*)d_in[4];
    const float* b_ih   = (const float*)d_in[5];
    const float* b_hh   = (const float*)d_in[6];
    const float* ln_g   = (const float*)d_in[7];
    const float* ln_b   = (const float*)d_in[8];
    const float* w1 = (const float*)d_in[9];  const float* b1 = (const float*)d_in[10];
    const float* w2 = (const float*)d_in[11]; const float* b2 = (const float*)d_in[12];
    const float* w3 = (const float*)d_in[13]; const float* b3 = (const float*)d_in[14];
    float* outp = (float*)d_out;

    char* ws = (char*)d_ws;
    size_t off = 0;
    auto alloc = [&](size_t sz) { char* p = ws + off; off += (sz + 255) & ~(size_t)255; return p; };
    unsigned short* a_bf   = (unsigned short*)alloc((size_t)32768 * 512 * 2);   //  33.5 MB
    float*          lstm_o = (float*)alloc((size_t)32768 * 512 * 4);            //  67   MB
    float*          hprev  = (float*)alloc((size_t)32768 * 512 * 4);            //  67   MB
    unsigned short* wih_bf = (unsigned short*)alloc((size_t)NL * 2048 * 512 * 2); // 12.6 MB
    unsigned short* whh_bf = (unsigned short*)alloc((size_t)NL * 2048 * 512 * 2); // 12.6 MB
    unsigned short* hbuf   = (unsigned short*)alloc((size_t)2 * 256 * 512 * 2);   // 0.5 MB
    float*          z1     = (float*)alloc((size_t)256 * 512 * 4);
    float*          z2     = (float*)alloc((size_t)256 * 256 * 4);
    unsigned int*   cnt    = (unsigned int*)alloc(2048 * 4);                      // 6 layers x 4 groups, 256B apart

    k_zero<<<8, 256, 0, stream>>>(cnt, 2048);
    k_convert<<<6144, 256, 0, stream>>>(w_ih, w_hh, wih_bf, whh_bf, (NL * 2048 * 512) / 4);
    k_proj<<<512, 512, 0, stream>>>(x, w_proj, b_proj, hprev, a_bf);

    for (int l = 0; l < NL; l++) {
        k_lstm_fused<<<128, 256, 0, stream>>>(wih_bf + (size_t)l * 2048 * 512,
                                              whh_bf + (size_t)l * 2048 * 512,
                                              a_bf, b_ih + l * 2048, b_hh + l * 2048,
                                              hbuf, lstm_o, cnt + l * 256);
        k_ln<<<8192, 256, 0, stream>>>(lstm_o, hprev, ln_g + l * 512, ln_b + l * 512,
                                       hprev, a_bf, l > 0 ? 1 : 0);
    }
    k_mlp1<<<256, 512, 0, stream>>>(hprev, w1, b1, z1);
    k_mlp2<<<256, 256, 0, stream>>>(z1, w2, b2, z2);
    k_mlp3<<<256, 256, 0, stream>>>(z2, w3, b3, outp);
}

// Round 3
// 8774.403 us; speedup vs baseline: 1.0578x; 1.0578x over previous
//
#include <hip/hip_runtime.h>
#include <hip/hip_bf16.h>
#include <stdint.h>

#define BB 256
#define TT 128
#define DD 32
#define HH 512
#define NL 6

typedef __attribute__((ext_vector_type(8))) short short8;
typedef __attribute__((ext_vector_type(4))) float f32x4;

__device__ __forceinline__ unsigned short f2bf(float f) {
    union { float f; unsigned u; } v; v.f = f;
    unsigned r = v.u + 0x7fff + ((v.u >> 16) & 1);
    return (unsigned short)(r >> 16);
}
__device__ __forceinline__ float fsig(float x) { return 1.0f / (1.0f + __expf(-x)); }
__device__ __forceinline__ float ftanh(float x) {
    float e = __expf(-2.0f * fabsf(x));
    float t = (1.0f - e) / (1.0f + e);
    return x < 0.0f ? -t : t;
}

// 16B / 8B global ops that bypass L1+L2 (coherent at Infinity Cache across XCDs)
__device__ __forceinline__ int4 g_load16_cc(const void* p) {
    int4 r;
    asm volatile("global_load_dwordx4 %0, %1, off sc0 sc1" : "=v"(r) : "v"(p) : "memory");
    return r;
}
__device__ __forceinline__ void g_store8_cc(void* p, unsigned long long v) {
    asm volatile("global_store_dwordx2 %0, %1, off sc0 sc1" :: "v"(p), "v"(v) : "memory");
}

// ---------------- zero the sync counters ----------------
__global__ __launch_bounds__(256) void k_zero(unsigned int* __restrict__ p, int n) {
    int i = blockIdx.x * 256 + threadIdx.x;
    if (i < n) p[i] = 0;
}

// ---------------- weight f32 -> bf16 ----------------
__global__ __launch_bounds__(256) void k_convert(const float* __restrict__ wih, const float* __restrict__ whh,
                                                 unsigned short* __restrict__ wih_bf, unsigned short* __restrict__ whh_bf,
                                                 int n4) {
    int i = blockIdx.x * 256 + threadIdx.x;
    if (i >= n4) return;
    float4 a = ((const float4*)wih)[i];
    float4 b = ((const float4*)whh)[i];
    ushort4 ra; ra.x = f2bf(a.x); ra.y = f2bf(a.y); ra.z = f2bf(a.z); ra.w = f2bf(a.w);
    ushort4 rb; rb.x = f2bf(b.x); rb.y = f2bf(b.y); rb.z = f2bf(b.z); rb.w = f2bf(b.w);
    ((ushort4*)wih_bf)[i] = ra;
    ((ushort4*)whh_bf)[i] = rb;
}

// ---------------- input projection: hprev = x @ w_proj.T + b ----------------
__global__ __launch_bounds__(512) void k_proj(const float* __restrict__ x, const float* __restrict__ wp,
                                              const float* __restrict__ bp,
                                              float* __restrict__ hprev, unsigned short* __restrict__ abf) {
    __shared__ float xs[64][DD];
    int m0 = blockIdx.x * 64;
    for (int i = threadIdx.x; i < 64 * DD; i += 512)
        xs[i >> 5][i & 31] = x[(size_t)(m0 + (i >> 5)) * DD + (i & 31)];
    __syncthreads();
    int n = threadIdx.x;
    float w[DD];
#pragma unroll
    for (int k = 0; k < DD; k++) w[k] = wp[n * DD + k];
    float bias = bp[n];
    for (int r = 0; r < 64; r++) {
        float acc = bias;
#pragma unroll
        for (int k = 0; k < DD; k++) acc += xs[r][k] * w[k];
        size_t o = (size_t)(m0 + r) * HH + n;
        hprev[o] = acc;
        abf[o] = f2bf(acc);
    }
}

// ---------------- fused persistent LSTM layer ----------------
__device__ __forceinline__ void do_burst(f32x4 (&X)[2][4], int TB,
                                         const unsigned short* __restrict__ wih_bf,
                                         const unsigned short* __restrict__ a_bf,
                                         int u0, int uu, int kg, int arow, const float* biasg) {
#pragma unroll
    for (int tt = 0; tt < 2; tt++)
#pragma unroll
        for (int g = 0; g < 4; g++) X[tt][g] = (f32x4){biasg[g], biasg[g], biasg[g], biasg[g]};
#pragma unroll
    for (int ks = 0; ks < 16; ks++) {
        short8 bfr[4];
#pragma unroll
        for (int g = 0; g < 4; g++)
            bfr[g] = *(const short8*)(wih_bf + (size_t)((g << 9) + u0 + uu) * 512 + ks * 32 + kg * 8);
#pragma unroll
        for (int tt = 0; tt < 2; tt++) {
            short8 afx = *(const short8*)(a_bf + ((size_t)arow * TT + (TB + tt)) * 512 + ks * 32 + kg * 8);
#pragma unroll
            for (int g = 0; g < 4; g++)
                X[tt][g] = __builtin_amdgcn_mfma_f32_16x16x32_bf16(afx, bfr[g], X[tt][g], 0, 0, 0);
        }
    }
}

__device__ __forceinline__ void do_step(int T, f32x4 (&XR)[4], f32x4& cst,
                                        const unsigned short* smem, unsigned short* hstage,
                                        unsigned short* __restrict__ hbuf, float* __restrict__ lstm_o,
                                        unsigned int* cntp,
                                        int tid, int w, int uu, int kg, int u0, int b0, int bx, int arow) {
    if (T > 0) {
        if (tid == 0) {
            unsigned target = 32u * (unsigned)T;
            int guard = 0;
            while (__hip_atomic_load(cntp, __ATOMIC_RELAXED, __HIP_MEMORY_SCOPE_AGENT) < target &&
                   ++guard < (1 << 18)) {}
        }
        __syncthreads();
        asm volatile("" ::: "memory");
        const unsigned short* hp = hbuf + (size_t)((T - 1) & 1) * (256 * 512);
        int4 ahi[16];
#pragma unroll
        for (int ks = 0; ks < 16; ks++)
            ahi[ks] = g_load16_cc(hp + (size_t)arow * 512 + ks * 32 + kg * 8);
        asm volatile("s_waitcnt vmcnt(0)" ::: "memory");
        __builtin_amdgcn_sched_barrier(0);
#pragma unroll
        for (int ks = 0; ks < 16; ks++) {
            short8 ah = *(short8*)&ahi[ks];
            const int k2 = (ks * 32 + kg * 8) * 2;
#pragma unroll
            for (int g = 0; g < 4; g++) {
                const int rr = (g << 4) + uu;
                const int baddr = (rr * 1024 + k2) ^ ((rr & 7) << 4);
                short8 bh = *(const short8*)((const char*)smem + baddr);
                XR[g] = __builtin_amdgcn_mfma_f32_16x16x32_bf16(ah, bh, XR[g], 0, 0, 0);
            }
        }
    }
    // activations: lane owns unit u0+uu, batches b0+kg*4+r
    float hval[4];
#pragma unroll
    for (int r = 0; r < 4; r++) {
        float i_ = fsig(XR[0][r]);
        float f_ = fsig(XR[1][r]);
        float g_ = ftanh(XR[2][r]);
        float o_ = fsig(XR[3][r]);
        float c = f_ * cst[r] + i_ * g_;
        cst[r] = c;
        hval[r] = o_ * ftanh(c);
    }
    // stage h tile (64 batches x 16 units) into LDS, then coalesced 8B cc-stores
#pragma unroll
    for (int r = 0; r < 4; r++)
        hstage[(w * 16 + kg * 4 + r) * 20 + uu] = f2bf(hval[r]);
    __syncthreads();
    {
        int bb = tid >> 2, uoff = (tid & 3) * 4;
        unsigned long long hv = *(const unsigned long long*)(hstage + bb * 20 + uoff);
        unsigned short* hw = hbuf + (size_t)(T & 1) * (256 * 512);
        g_store8_cc(hw + (size_t)(bx * 64 + bb) * 512 + u0 + uoff, hv);
    }
    asm volatile("s_waitcnt vmcnt(0)" ::: "memory");
    __syncthreads();
    if (T < TT - 1 && tid == 0)
        __hip_atomic_fetch_add(cntp, 1u, __ATOMIC_RELAXED, __HIP_MEMORY_SCOPE_AGENT);
    // lstm_o stores off the inter-block critical path
#pragma unroll
    for (int r = 0; r < 4; r++) {
        int b = b0 + kg * 4 + r;
        lstm_o[((size_t)b * TT + T) * 512 + u0 + uu] = hval[r];
    }
}

__global__ __launch_bounds__(256) void k_lstm_fused(const unsigned short* __restrict__ wih_bf,
                                                    const unsigned short* __restrict__ whh_bf,
                                                    const unsigned short* __restrict__ a_bf,
                                                    const float* __restrict__ bih, const float* __restrict__ bhh,
                                                    unsigned short* __restrict__ hbuf,
                                                    float* __restrict__ lstm_o,
                                                    unsigned int* __restrict__ cnt) {
    __shared__ unsigned short smem[64 * 512];     // whh slice, XOR-swizzled
    __shared__ unsigned short hstage[64 * 20];    // h transpose staging
    const int blk = blockIdx.x;
    const int bx = (blk & 7) >> 1;
    const int ux = ((blk >> 3) << 1) | (blk & 1);
    const int tid = threadIdx.x, lane = tid & 63, w = tid >> 6;
    const int u0 = ux * 16;
    const int b0 = bx * 64 + w * 16;
    const int uu = lane & 15;
    const int kg = lane >> 4;
    unsigned int* cntp = cnt + bx * 64;

    for (int c = tid; c < 64 * 64; c += 256) {
        int rr = c >> 6, k16 = c & 63;
        int grow = ((rr >> 4) << 9) + u0 + (rr & 15);
        int4 v = *(const int4*)(whh_bf + (size_t)grow * 512 + k16 * 8);
        int baddr = (rr * 1024 + k16 * 16) ^ ((rr & 7) << 4);
        *(int4*)((char*)smem + baddr) = v;
    }
    __syncthreads();

    float biasg[4];
#pragma unroll
    for (int g = 0; g < 4; g++) biasg[g] = bih[(g << 9) + u0 + uu] + bhh[(g << 9) + u0 + uu];

    const int arow = b0 + uu;
    f32x4 cst = (f32x4){0.f, 0.f, 0.f, 0.f};
    f32x4 xA[2][4], xB[2][4];

    do_burst(xA, 0, wih_bf, a_bf, u0, uu, kg, arow, biasg);

#pragma unroll 1
    for (int tc = 0; tc < TT; tc += 4) {
        do_step(tc + 0, xA[0], cst, smem, hstage, hbuf, lstm_o, cntp, tid, w, uu, kg, u0, b0, bx, arow);
        do_burst(xB, tc + 2, wih_bf, a_bf, u0, uu, kg, arow, biasg);
        do_step(tc + 1, xA[1], cst, smem, hstage, hbuf, lstm_o, cntp, tid, w, uu, kg, u0, b0, bx, arow);
        do_step(tc + 2, xB[0], cst, smem, hstage, hbuf, lstm_o, cntp, tid, w, uu, kg, u0, b0, bx, arow);
        if (tc + 4 < TT)
            do_burst(xA, tc + 4, wih_bf, a_bf, u0, uu, kg, arow, biasg);
        do_step(tc + 3, xB[1], cst, smem, hstage, hbuf, lstm_o, cntp, tid, w, uu, kg, u0, b0, bx, arow);
    }
}

// ---------------- LayerNorm + residual; also emit bf16 copy for next layer ----------------
__global__ __launch_bounds__(256) void k_ln(const float* __restrict__ xin, const float* __restrict__ resid,
                                            const float* __restrict__ g, const float* __restrict__ bta,
                                            float* __restrict__ hnew, unsigned short* __restrict__ abf,
                                            int do_res) {
    int row = blockIdx.x * 4 + (threadIdx.x >> 6);
    int lane = threadIdx.x & 63;
    const float* xr = xin + (size_t)row * 512;
    float vals[8];
    float s = 0.f, ss = 0.f;
#pragma unroll
    for (int i = 0; i < 2; i++) {
        float4 t = *(const float4*)(xr + lane * 8 + i * 4);
        vals[i * 4 + 0] = t.x; vals[i * 4 + 1] = t.y; vals[i * 4 + 2] = t.z; vals[i * 4 + 3] = t.w;
        s += t.x + t.y + t.z + t.w;
        ss += t.x * t.x + t.y * t.y + t.z * t.z + t.w * t.w;
    }
#pragma unroll
    for (int off = 32; off > 0; off >>= 1) {
        s += __shfl_down(s, off);
        ss += __shfl_down(ss, off);
    }
    s = __shfl(s, 0); ss = __shfl(ss, 0);
    float mu = s * (1.f / 512.f);
    float var = ss * (1.f / 512.f) - mu * mu;
    float rs = rsqrtf(var + 1e-5f);
#pragma unroll
    for (int i = 0; i < 8; i++) {
        int u = lane * 8 + i;
        float y = (vals[i] - mu) * rs * g[u] + bta[u];
        if (do_res) y += resid[(size_t)row * 512 + u];
        hnew[(size_t)row * 512 + u] = y;
        abf[(size_t)row * 512 + u] = f2bf(y);
    }
}

// ---------------- MLP head ----------------
__global__ __launch_bounds__(512) void k_mlp1(const float* __restrict__ hprev, const float* __restrict__ w1,
                                              const float* __restrict__ b1, float* __restrict__ z1) {
    __shared__ float xs[512];
    int b = blockIdx.x;
    const float* xr = hprev + ((size_t)b * TT + (TT - 1)) * 512;
    xs[threadIdx.x] = xr[threadIdx.x];
    __syncthreads();
    int n = threadIdx.x;
    const float4* wr = (const float4*)(w1 + (size_t)n * 512);
    float acc = b1[n];
#pragma unroll 4
    for (int k4 = 0; k4 < 128; k4++) {
        float4 wv = wr[k4];
        acc += xs[k4 * 4 + 0] * wv.x + xs[k4 * 4 + 1] * wv.y + xs[k4 * 4 + 2] * wv.z + xs[k4 * 4 + 3] * wv.w;
    }
    z1[(size_t)b * 512 + n] = fmaxf(acc, 0.f);
}

__global__ __launch_bounds__(256) void k_mlp2(const float* __restrict__ z1, const float* __restrict__ w2,
                                              const float* __restrict__ b2, float* __restrict__ z2) {
    __shared__ float xs[512];
    int b = blockIdx.x;
    xs[threadIdx.x] = z1[(size_t)b * 512 + threadIdx.x];
    xs[threadIdx.x + 256] = z1[(size_t)b * 512 + threadIdx.x + 256];
    __syncthreads();
    int n = threadIdx.x;
    const float4* wr = (const float4*)(w2 + (size_t)n * 512);
    float acc = b2[n];
#pragma unroll 4
    for (int k4 = 0; k4 < 128; k4++) {
        float4 wv = wr[k4];
        acc += xs[k4 * 4 + 0] * wv.x + xs[k4 * 4 + 1] * wv.y + xs[k4 * 4 + 2] * wv.z + xs[k4 * 4 + 3] * wv.w;
    }
    z2[(size_t)b * 256 + n] = fmaxf(acc, 0.f);
}

__global__ __launch_bounds__(256) void k_mlp3(const float* __restrict__ z2, const float* __restrict__ w3,
                                              const float* __restrict__ b3, float* __restrict__ outp) {
    __shared__ float red[4];
    int b = blockIdx.x;
    int tid = threadIdx.x;
    float p = z2[(size_t)b * 256 + tid] * w3[tid];
#pragma unroll
    for (int off = 32; off > 0; off >>= 1) p += __shfl_down(p, off);
    if ((tid & 63) == 0) red[tid >> 6] = p;
    __syncthreads();
    if (tid == 0) outp[b] = red[0] + red[1] + red[2] + red[3] + b3[0];
}

extern "C" void kernel_launch(void* const* d_in, const int* in_sizes, int n_in,
                              void* d_out, int out_size, void* d_ws, size_t ws_size,
                              hipStream_t stream) {
    const float* x      = (const float*)d_in[0];
    const float* w_proj = (const float*)d_in[1];
    const float* b_proj = (const float*)d_in[2];
    const float* w_ih   = (const float*)d_in[3];
    const float* w_hh   = (const float*)d_in[4];
    const float* b_ih   = (const float*)d_in[5];
    const float* b_hh   = (const float*)d_in[6];
    const float* ln_g   = (const float*)d_in[7];
    const float* ln_b   = (const float*)d_in[8];
    const float* w1 = (const float*)d_in[9];  const float* b1 = (const float*)d_in[10];
    const float* w2 = (const float*)d_in[11]; const float* b2 = (const float*)d_in[12];
    const float* w3 = (const float*)d_in[13]; const float* b3 = (const float*)d_in[14];
    float* outp = (float*)d_out;

    char* ws = (char*)d_ws;
    size_t off = 0;
    auto alloc = [&](size_t sz) { char* p = ws + off; off += (sz + 255) & ~(size_t)255; return p; };
    unsigned short* a_bf   = (unsigned short*)alloc((size_t)32768 * 512 * 2);
    float*          lstm_o = (float*)alloc((size_t)32768 * 512 * 4);
    float*          hprev  = (float*)alloc((size_t)32768 * 512 * 4);
    unsigned short* wih_bf = (unsigned short*)alloc((size_t)NL * 2048 * 512 * 2);
    unsigned short* whh_bf = (unsigned short*)alloc((size_t)NL * 2048 * 512 * 2);
    unsigned short* hbuf   = (unsigned short*)alloc((size_t)2 * 256 * 512 * 2);
    float*          z1     = (float*)alloc((size_t)256 * 512 * 4);
    float*          z2     = (float*)alloc((size_t)256 * 256 * 4);
    unsigned int*   cnt    = (unsigned int*)alloc(2048 * 4);

    k_zero<<<8, 256, 0, stream>>>(cnt, 2048);
    k_convert<<<6144, 256, 0, stream>>>(w_ih, w_hh, wih_bf, whh_bf, (NL * 2048 * 512) / 4);
    k_proj<<<512, 512, 0, stream>>>(x, w_proj, b_proj, hprev, a_bf);

    for (int l = 0; l < NL; l++) {
        k_lstm_fused<<<128, 256, 0, stream>>>(wih_bf + (size_t)l * 2048 * 512,
                                              whh_bf + (size_t)l * 2048 * 512,
                                              a_bf, b_ih + l * 2048, b_hh + l * 2048,
                                              hbuf, lstm_o, cnt + l * 256);
        k_ln<<<8192, 256, 0, stream>>>(lstm_o, hprev, ln_g + l * 512, ln_b + l * 512,
                                       hprev, a_bf, l > 0 ? 1 : 0);
    }
    k_mlp1<<<256, 512, 0, stream>>>(hprev, w1, b1, z1);
    k_mlp2<<<256, 256, 0, stream>>>(z1, w2, b2, z2);
    k_mlp3<<<256, 256, 0, stream>>>(z2, w3, b3, outp);
}